// Round 2
// baseline (1052.251 us; speedup 1.0000x reference)
//
#include <hip/hip_runtime.h>
#include <math.h>

namespace {

constexpr int B_      = 65536;
constexpr int OBS_DIM_= 85;
constexpr int FEAT_   = 8;
constexpr int NL_     = 5;
constexpr int NT_     = 10;
constexpr int INF_    = 64;
constexpr int HID_    = 64;
constexpr int NACT_   = 5;
constexpr float ALPHA_= 0.01f;

__device__ __forceinline__ float leaky(float x)    { return x > 0.0f ? x : ALPHA_ * x; }
__device__ __forceinline__ float sigmoidf(float x) { return 1.0f / (1.0f + __expf(-x)); }
// tanh(x) = 1 - 2/(exp(2x)+1); exp overflow -> inf -> 1, exp->0 -> -1 (correct limits)
__device__ __forceinline__ float tanh_fast(float x){ return 1.0f - 2.0f / (__expf(2.0f * x) + 1.0f); }

// ---------------------------------------------------------------------------
// Tiny precompute: Wa1[i] = sum_j W[i][j]*a[j], Wa2[i] = sum_j W[i][j]*a[64+j]
// Removes the (B,10,64)@(64,64) matmul entirely: (h_mix@W)@a == h_mix@(W@a).
// ---------------------------------------------------------------------------
__global__ void precompute_Wa(const float* __restrict__ W,
                              const float* __restrict__ a,
                              float* __restrict__ Wa) {
  int i = threadIdx.x;  // 64 threads
  float s1 = 0.0f, s2 = 0.0f;
  #pragma unroll
  for (int j = 0; j < INF_; ++j) {
    float w = W[i * INF_ + j];
    s1 += w * a[j];
    s2 += w * a[INF_ + j];
  }
  Wa[i] = s1;
  Wa[INF_ + i] = s2;
}

// Per time-step t: Wh1[t] = leaky(obs_in[t]@w+b) . Wa1 ; Wh2 likewise.
__device__ __forceinline__ void stage1_t(const float* __restrict__ ob, int t,
                                         const float* __restrict__ w,
                                         const float* __restrict__ bv,
                                         const float* __restrict__ Wa,
                                         float& s1, float& s2) {
  float ov[FEAT_];
  #pragma unroll
  for (int f = 0; f < FEAT_; ++f) {
    int j = t * FEAT_ + f + 4;        // obs_in[j] = o[(j+4) mod 80]
    if (j >= 80) j -= 80;
    ov[f] = ob[j];
  }
  float a1 = 0.0f, a2 = 0.0f;
  #pragma unroll 8
  for (int i = 0; i < INF_; ++i) {    // weight addrs wave-uniform -> s_load
    float z = bv[i];
    #pragma unroll
    for (int f = 0; f < FEAT_; ++f) z += ov[f] * w[f * INF_ + i];
    float hm = leaky(z);
    a1 += hm * Wa[i];
    a2 += hm * Wa[INF_ + i];
  }
  s1 = a1; s2 = a2;
}

// block=64: 1024 workgroups so all 256 CUs can hold multiple blocks
// (256-thread blocks gave exactly 1 wg/CU -> 12% occupancy, grid-limited).
__global__ __launch_bounds__(64) void atom_rnn_fused(
    const float* __restrict__ obs, const float* __restrict__ hidden,
    const float* __restrict__ w_in0, const float* __restrict__ b_in0,
    const float* __restrict__ w_in1, const float* __restrict__ b_in1,
    const float* __restrict__ w_in2, const float* __restrict__ b_in2,
    const float* __restrict__ Wa,
    const float* __restrict__ w_o1, const float* __restrict__ b_o1,
    const float* __restrict__ w_o2, const float* __restrict__ b_o2,
    const float* __restrict__ w_o3, const float* __restrict__ b_o3,
    const float* __restrict__ w_fc1, const float* __restrict__ b_fc1,
    const float* __restrict__ w_ih, const float* __restrict__ w_hh,
    const float* __restrict__ b_ih, const float* __restrict__ b_hh,
    const float* __restrict__ w_fc2, const float* __restrict__ b_fc2,
    float* __restrict__ q_out, float* __restrict__ h_out) {

  const int b = blockIdx.x * blockDim.x + threadIdx.x;
  if (b >= B_) return;
  const float* ob = obs + (long)b * OBS_DIM_;

  // ---- Stage 1: Wh1[10], Wh2[10] ----
  float Wh1[NT_], Wh2[NT_];
  #pragma unroll
  for (int t = 0; t < NL_; ++t)        stage1_t(ob, t, w_in0, b_in0, Wa, Wh1[t], Wh2[t]);
  #pragma unroll
  for (int t = NL_; t < NT_ - 1; ++t)  stage1_t(ob, t, w_in1, b_in1, Wa, Wh1[t], Wh2[t]);
  stage1_t(ob, NT_ - 1, w_in2, b_in2, Wa, Wh1[NT_ - 1], Wh2[NT_ - 1]);

  // ---- Attention: e[i][j] = leaky(Wh1[i] + Wh2[j]) ----
  // att1 column softmaxes (shared across rows): softmax_k e[5+jj][k]
  float colm[NL_], cols_[NL_];
  #pragma unroll
  for (int jj = 0; jj < NL_; ++jj) {
    float ev[NL_], m = -1e30f;
    #pragma unroll
    for (int k = 0; k < NL_; ++k) { ev[k] = leaky(Wh1[NL_ + jj] + Wh2[k]); m = fmaxf(m, ev[k]); }
    float s = 0.0f;
    #pragma unroll
    for (int k = 0; k < NL_; ++k) s += __expf(ev[k] - m);
    colm[jj] = m; cols_[jj] = s;
  }

  float hp3[NL_];
  #pragma unroll
  for (int r = 0; r < NL_; ++r) {
    float att[NT_];
    // att0 row r: softmax_j e[r][5+j]
    float ev[NL_], m = -1e30f;
    #pragma unroll
    for (int j = 0; j < NL_; ++j) { ev[j] = leaky(Wh1[r] + Wh2[NL_ + j]); m = fmaxf(m, ev[j]); }
    float s = 0.0f;
    #pragma unroll
    for (int j = 0; j < NL_; ++j) { float e = __expf(ev[j] - m); att[j] = e; s += e; }
    float inv = 1.0f / s;
    #pragma unroll
    for (int j = 0; j < NL_; ++j) att[j] *= inv;
    // att1 part: exp(e[5+jj][r]-colm)/cols
    #pragma unroll
    for (int jj = 0; jj < NL_; ++jj) {
      float e = leaky(Wh1[NL_ + jj] + Wh2[r]);
      att[NL_ + jj] = __expf(e - colm[jj]) / cols_[jj];
    }
    // 10 -> 32 -> 16 -> 1 MLP (fully unrolled: keep arrays in registers)
    float h1v[32];
    #pragma unroll
    for (int c = 0; c < 32; ++c) {
      float z = b_o1[c];
      #pragma unroll
      for (int k = 0; k < NT_; ++k) z += att[k] * w_o1[k * 32 + c];
      h1v[c] = leaky(z);
    }
    float h2v[16];
    #pragma unroll
    for (int c = 0; c < 16; ++c) {
      float z = b_o2[c];
      #pragma unroll
      for (int k = 0; k < 32; ++k) z += h1v[k] * w_o2[k * 16 + c];
      h2v[c] = leaky(z);
    }
    float z3 = b_o3[0];
    #pragma unroll
    for (int k = 0; k < 16; ++k) z3 += h2v[k] * w_o3[k];
    hp3[r] = leaky(z3);
  }

  // obs_out = softmax(hp3)
  float m5 = hp3[0];
  #pragma unroll
  for (int r = 1; r < NL_; ++r) m5 = fmaxf(m5, hp3[r]);
  float obs_out[NL_], ssum = 0.0f;
  #pragma unroll
  for (int r = 0; r < NL_; ++r) { obs_out[r] = __expf(hp3[r] - m5); ssum += obs_out[r]; }
  float sinv = 1.0f / ssum;
  #pragma unroll
  for (int r = 0; r < NL_; ++r) obs_out[r] *= sinv;

  // ---- fc1: x = relu([obs, obs_out] @ w_fc1 + b_fc1) ----
  float x[HID_];
  #pragma unroll
  for (int i = 0; i < HID_; ++i) x[i] = b_fc1[i];
  for (int k = 0; k < OBS_DIM_; ++k) {
    float o = ob[k];
    #pragma unroll
    for (int i = 0; i < HID_; ++i) x[i] += o * w_fc1[k * HID_ + i];
  }
  #pragma unroll
  for (int k = 0; k < NL_; ++k) {
    float o = obs_out[k];
    #pragma unroll
    for (int i = 0; i < HID_; ++i) x[i] += o * w_fc1[(OBS_DIM_ + k) * HID_ + i];
  }
  #pragma unroll
  for (int i = 0; i < HID_; ++i) x[i] = fmaxf(x[i], 0.0f);

  // ---- GRU, gate-row-wise + fused q ----
  // hv[] is ONLY read at constant (unrolled) indices -> register-promoted.
  // The one dynamic-index use (old h at gate i) re-reads hidden[] from
  // global (L1-hot) instead of hv[i], which previously forced the whole
  // array into scratch (267 MB of spill WRITE_SIZE in round 1).
  const float* hrow = hidden + (long)b * HID_;
  float hv[HID_];
  #pragma unroll
  for (int i = 0; i < HID_; ++i) hv[i] = hrow[i];

  float q[NACT_];
  #pragma unroll
  for (int c = 0; c < NACT_; ++c) q[c] = b_fc2[c];

  for (int i = 0; i < HID_; ++i) {
    float gi_r = b_ih[i], gi_z = b_ih[HID_ + i], gi_n = b_ih[2 * HID_ + i];
    float gh_r = b_hh[i], gh_z = b_hh[HID_ + i], gh_n = b_hh[2 * HID_ + i];
    const float* wi_r = w_ih + (long)i * HID_;
    const float* wi_z = w_ih + (long)(HID_ + i) * HID_;
    const float* wi_n = w_ih + (long)(2 * HID_ + i) * HID_;
    const float* wh_r = w_hh + (long)i * HID_;
    const float* wh_z = w_hh + (long)(HID_ + i) * HID_;
    const float* wh_n = w_hh + (long)(2 * HID_ + i) * HID_;
    #pragma unroll
    for (int k = 0; k < HID_; ++k) {
      float xk = x[k], hk = hv[k];
      gi_r += xk * wi_r[k];
      gi_z += xk * wi_z[k];
      gi_n += xk * wi_n[k];
      gh_r += hk * wh_r[k];
      gh_z += hk * wh_z[k];
      gh_n += hk * wh_n[k];
    }
    float r_ = sigmoidf(gi_r + gh_r);
    float z_ = sigmoidf(gi_z + gh_z);
    float n_ = tanh_fast(gi_n + r_ * gh_n);
    float h_ = (1.0f - z_) * n_ + z_ * hrow[i];   // global re-read, L1-hot
    h_out[(long)b * HID_ + i] = h_;
    #pragma unroll
    for (int c = 0; c < NACT_; ++c) q[c] += h_ * w_fc2[i * NACT_ + c];
  }
  #pragma unroll
  for (int c = 0; c < NACT_; ++c) q_out[(long)b * NACT_ + c] = q[c];
}

}  // namespace

extern "C" void kernel_launch(void* const* d_in, const int* in_sizes, int n_in,
                              void* d_out, int out_size, void* d_ws, size_t ws_size,
                              hipStream_t stream) {
  const float* obs    = (const float*)d_in[0];
  const float* hidden = (const float*)d_in[1];
  const float* w_in0  = (const float*)d_in[2];
  const float* b_in0  = (const float*)d_in[3];
  const float* w_in1  = (const float*)d_in[4];
  const float* b_in1  = (const float*)d_in[5];
  const float* w_in2  = (const float*)d_in[6];
  const float* b_in2  = (const float*)d_in[7];
  const float* W      = (const float*)d_in[8];
  const float* a      = (const float*)d_in[9];
  const float* w_o1   = (const float*)d_in[10];
  const float* b_o1   = (const float*)d_in[11];
  const float* w_o2   = (const float*)d_in[12];
  const float* b_o2   = (const float*)d_in[13];
  const float* w_o3   = (const float*)d_in[14];
  const float* b_o3   = (const float*)d_in[15];
  const float* w_fc1  = (const float*)d_in[16];
  const float* b_fc1  = (const float*)d_in[17];
  const float* w_ih   = (const float*)d_in[18];
  const float* w_hh   = (const float*)d_in[19];
  const float* b_ih   = (const float*)d_in[20];
  const float* b_hh   = (const float*)d_in[21];
  const float* w_fc2  = (const float*)d_in[22];
  const float* b_fc2  = (const float*)d_in[23];

  float* q_out = (float*)d_out;                  // (B, 5) flat
  float* h_out = q_out + (long)B_ * NACT_;       // (B, 64) flat

  float* Wa = (float*)d_ws;                      // 128 floats scratch

  precompute_Wa<<<1, 64, 0, stream>>>(W, a, Wa);
  atom_rnn_fused<<<B_ / 64, 64, 0, stream>>>(
      obs, hidden, w_in0, b_in0, w_in1, b_in1, w_in2, b_in2, Wa,
      w_o1, b_o1, w_o2, b_o2, w_o3, b_o3, w_fc1, b_fc1,
      w_ih, w_hh, b_ih, b_hh, w_fc2, b_fc2, q_out, h_out);
}

// Round 3
// 982.420 us; speedup vs baseline: 1.0711x; 1.0711x over previous
//
#include <hip/hip_runtime.h>
#include <math.h>

namespace {

constexpr int B_      = 65536;
constexpr int OBS_DIM_= 85;
constexpr int NL_     = 5;
constexpr int NT_     = 10;
constexpr int HID_    = 64;
constexpr int NACT_   = 5;
constexpr float ALPHA_= 0.01f;

constexpr int ROWS_ = 32;          // rows per block
constexpr int BLK_  = ROWS_ * 8;   // 256 threads, 8 lanes cooperate per row
constexpr int OBS_S = 85;          // obs LDS stride: 85%32=21 -> 8 groups hit distinct banks
constexpr int XS_   = 68;          // x/h LDS stride: 68%32=4  -> groups at banks 0,4,..,28

__device__ __forceinline__ float leaky(float x)    { return x > 0.0f ? x : ALPHA_ * x; }
__device__ __forceinline__ float sigmoidf(float x) { return 1.0f / (1.0f + __expf(-x)); }
__device__ __forceinline__ float tanh_fast(float x){ return 1.0f - 2.0f / (__expf(2.0f * x) + 1.0f); }

// Wa1[i] = sum_j W[i][j]*a[j], Wa2[i] = sum_j W[i][j]*a[64+j]
// (h_mix@W)@a == h_mix@(W@a): removes the (B,10,64)@(64,64) matmul.
__global__ void precompute_Wa(const float* __restrict__ W,
                              const float* __restrict__ a,
                              float* __restrict__ Wa) {
  int i = threadIdx.x;  // 64 threads
  float s1 = 0.0f, s2 = 0.0f;
  #pragma unroll
  for (int j = 0; j < 64; ++j) {
    float w = W[i * 64 + j];
    s1 += w * a[j];
    s2 += w * a[64 + j];
  }
  Wa[i] = s1;
  Wa[64 + i] = s2;
}

// Stage 1 for t in [T0,T1): lane handles 8 of the 64 INF units (slice = sub*8).
// T0/T1 are template params so p1[t]/p2[t] stay constant-indexed (no scratch).
template <int T0, int T1>
__device__ __forceinline__ void stage1_class(
    const float* __restrict__ wc, const float* __restrict__ bc,
    const float* obs_row, int sub,
    const float wa1[8], const float wa2[8],
    float (&p1)[NT_], float (&p2)[NT_]) {
  float bb[8];
  #pragma unroll
  for (int j = 0; j < 8; ++j) bb[j] = bc[sub * 8 + j];
  #pragma unroll
  for (int t = T0; t < T1; ++t) {
    float ov[8];
    #pragma unroll
    for (int f = 0; f < 8; ++f) {
      int j = t * 8 + f + 4;            // obs_in[j] = o[(j+4) mod 80]
      if (j >= 80) j -= 80;             // compile-time after unroll
      ov[f] = obs_row[j];
    }
    float z[8];
    #pragma unroll
    for (int j = 0; j < 8; ++j) z[j] = bb[j];
    #pragma unroll
    for (int f = 0; f < 8; ++f) {
      #pragma unroll
      for (int j = 0; j < 8; ++j) z[j] += ov[f] * wc[f * 64 + sub * 8 + j];
    }
    float a1 = 0.0f, a2 = 0.0f;
    #pragma unroll
    for (int j = 0; j < 8; ++j) {
      float hm = leaky(z[j]);
      a1 += hm * wa1[j];
      a2 += hm * wa2[j];
    }
    p1[t] = a1; p2[t] = a2;
  }
}

__global__ __launch_bounds__(BLK_) void atom_rnn_fused(
    const float* __restrict__ obs, const float* __restrict__ hidden,
    const float* __restrict__ w_in0, const float* __restrict__ b_in0,
    const float* __restrict__ w_in1, const float* __restrict__ b_in1,
    const float* __restrict__ w_in2, const float* __restrict__ b_in2,
    const float* __restrict__ Wa,
    const float* __restrict__ w_o1, const float* __restrict__ b_o1,
    const float* __restrict__ w_o2, const float* __restrict__ b_o2,
    const float* __restrict__ w_o3, const float* __restrict__ b_o3,
    const float* __restrict__ w_fc1, const float* __restrict__ b_fc1,
    const float* __restrict__ w_ih, const float* __restrict__ w_hh,
    const float* __restrict__ b_ih, const float* __restrict__ b_hh,
    const float* __restrict__ w_fc2, const float* __restrict__ b_fc2,
    float* __restrict__ q_out, float* __restrict__ h_out) {

  __shared__ float obs_s[ROWS_ * OBS_S];
  __shared__ float h_s[ROWS_ * XS_];
  __shared__ float x_s[ROWS_ * XS_];

  const int tid = threadIdx.x;
  const int row_local = tid >> 3;       // 0..31; lanes of a row are contiguous in wave
  const int sub = tid & 7;              // 0..7
  const int lane = tid & 63;
  const long row0 = (long)blockIdx.x * ROWS_;
  const long b = row0 + row_local;

  // ---- cooperative staging (coalesced) ----
  {
    const float* src = obs + row0 * OBS_DIM_;
    for (int idx = tid; idx < ROWS_ * OBS_DIM_; idx += BLK_) obs_s[idx] = src[idx];
    const float* hsrc = hidden + row0 * HID_;
    for (int idx = tid; idx < ROWS_ * HID_; idx += BLK_) {
      int r = idx >> 6, k = idx & 63;
      h_s[r * XS_ + k] = hsrc[idx];
    }
  }
  __syncthreads();

  const float* obs_row = &obs_s[row_local * OBS_S];

  // ---- Stage 1: partial Wh1/Wh2 over my 8 INF units ----
  float wa1[8], wa2[8];
  #pragma unroll
  for (int j = 0; j < 8; ++j) { wa1[j] = Wa[sub * 8 + j]; wa2[j] = Wa[64 + sub * 8 + j]; }

  float p1[NT_], p2[NT_];
  stage1_class<0, 5>(w_in0, b_in0, obs_row, sub, wa1, wa2, p1, p2);
  stage1_class<5, 9>(w_in1, b_in1, obs_row, sub, wa1, wa2, p1, p2);
  stage1_class<9, 10>(w_in2, b_in2, obs_row, sub, wa1, wa2, p1, p2);

  // butterfly-reduce within each 8-lane row group -> all lanes get full Wh1/Wh2
  #pragma unroll
  for (int m = 1; m < 8; m <<= 1) {
    #pragma unroll
    for (int t = 0; t < NT_; ++t) {
      p1[t] += __shfl_xor(p1[t], m, 64);
      p2[t] += __shfl_xor(p2[t], m, 64);
    }
  }

  // ---- attention (each lane: one of the 5 output rows; lanes 5-7 duplicate) ----
  float colm[NL_], cols_[NL_];
  #pragma unroll
  for (int jj = 0; jj < NL_; ++jj) {
    float ev[NL_], m = -1e30f;
    #pragma unroll
    for (int k = 0; k < NL_; ++k) { ev[k] = leaky(p1[NL_ + jj] + p2[k]); m = fmaxf(m, ev[k]); }
    float s = 0.0f;
    #pragma unroll
    for (int k = 0; k < NL_; ++k) s += __expf(ev[k] - m);
    colm[jj] = m; cols_[jj] = s;
  }

  const int r = (sub < 5) ? sub : sub - 5;
  float wh1_r = p1[0], wh2_r = p2[0];          // cndmask select: no dynamic reg index
  if (r == 1) { wh1_r = p1[1]; wh2_r = p2[1]; }
  if (r == 2) { wh1_r = p1[2]; wh2_r = p2[2]; }
  if (r == 3) { wh1_r = p1[3]; wh2_r = p2[3]; }
  if (r == 4) { wh1_r = p1[4]; wh2_r = p2[4]; }

  float att[NT_];
  {
    float ev[NL_], m = -1e30f;
    #pragma unroll
    for (int j = 0; j < NL_; ++j) { ev[j] = leaky(wh1_r + p2[NL_ + j]); m = fmaxf(m, ev[j]); }
    float s = 0.0f;
    #pragma unroll
    for (int j = 0; j < NL_; ++j) { float e = __expf(ev[j] - m); att[j] = e; s += e; }
    float inv = 1.0f / s;
    #pragma unroll
    for (int j = 0; j < NL_; ++j) att[j] *= inv;
    #pragma unroll
    for (int jj = 0; jj < NL_; ++jj) {
      float e = leaky(p1[NL_ + jj] + wh2_r);
      att[NL_ + jj] = __expf(e - colm[jj]) / cols_[jj];
    }
  }

  // 10 -> 32 -> 16 -> 1 MLP (weights lane-uniform -> scalar loads)
  float hp3_local;
  {
    float h1v[32];
    #pragma unroll
    for (int c = 0; c < 32; ++c) {
      float z = b_o1[c];
      #pragma unroll
      for (int k = 0; k < NT_; ++k) z += att[k] * w_o1[k * 32 + c];
      h1v[c] = leaky(z);
    }
    float h2v[16];
    #pragma unroll
    for (int c = 0; c < 16; ++c) {
      float z = b_o2[c];
      #pragma unroll
      for (int k = 0; k < 32; ++k) z += h1v[k] * w_o2[k * 16 + c];
      h2v[c] = leaky(z);
    }
    float z3 = b_o3[0];
    #pragma unroll
    for (int k = 0; k < 16; ++k) z3 += h2v[k] * w_o3[k];
    hp3_local = leaky(z3);
  }

  // gather hp3 from lanes 0..4 of my group, softmax (redundant per lane)
  float obs_out[NL_];
  {
    const int base = lane & ~7;
    float hp[NL_];
    #pragma unroll
    for (int j = 0; j < NL_; ++j) hp[j] = __shfl(hp3_local, base + j, 64);
    float m5 = hp[0];
    #pragma unroll
    for (int j = 1; j < NL_; ++j) m5 = fmaxf(m5, hp[j]);
    float s = 0.0f;
    #pragma unroll
    for (int j = 0; j < NL_; ++j) { obs_out[j] = __expf(hp[j] - m5); s += obs_out[j]; }
    float inv = 1.0f / s;
    #pragma unroll
    for (int j = 0; j < NL_; ++j) obs_out[j] *= inv;
  }

  // ---- fc1: my 8 output units ----
  const int u0 = sub * 8;
  float xa[8];
  #pragma unroll
  for (int j = 0; j < 8; ++j) xa[j] = b_fc1[u0 + j];
  #pragma unroll 5
  for (int k = 0; k < OBS_DIM_; ++k) {
    float o = obs_row[k];
    #pragma unroll
    for (int j = 0; j < 8; ++j) xa[j] += o * w_fc1[k * 64 + u0 + j];
  }
  #pragma unroll
  for (int k = 0; k < NL_; ++k) {
    float o = obs_out[k];
    #pragma unroll
    for (int j = 0; j < 8; ++j) xa[j] += o * w_fc1[(OBS_DIM_ + k) * 64 + u0 + j];
  }
  #pragma unroll
  for (int j = 0; j < 8; ++j) {
    xa[j] = fmaxf(xa[j], 0.0f);
    x_s[row_local * XS_ + u0 + j] = xa[j];   // same-wave producer/consumer: no barrier
  }

  // ---- GRU: my 8 h-units; combined r/z accumulators (bias_ih+bias_hh) ----
  float ar[8], az[8], ani[8], anh[8];
  #pragma unroll
  for (int j = 0; j < 8; ++j) {
    ar[j]  = b_ih[u0 + j]       + b_hh[u0 + j];
    az[j]  = b_ih[64 + u0 + j]  + b_hh[64 + u0 + j];
    ani[j] = b_ih[128 + u0 + j];
    anh[j] = b_hh[128 + u0 + j];
  }
  const float* xrow = &x_s[row_local * XS_];
  const float* hrow = &h_s[row_local * XS_];
  #pragma unroll 2
  for (int k4 = 0; k4 < 16; ++k4) {
    const float4 x4 = *(const float4*)&xrow[k4 * 4];
    const float4 h4 = *(const float4*)&hrow[k4 * 4];
    #pragma unroll
    for (int j = 0; j < 8; ++j) {
      const int u = u0 + j;
      const float4 wir = *(const float4*)&w_ih[(long)u * 64 + k4 * 4];
      const float4 wiz = *(const float4*)&w_ih[(long)(64 + u) * 64 + k4 * 4];
      const float4 win = *(const float4*)&w_ih[(long)(128 + u) * 64 + k4 * 4];
      const float4 whr = *(const float4*)&w_hh[(long)u * 64 + k4 * 4];
      const float4 whz = *(const float4*)&w_hh[(long)(64 + u) * 64 + k4 * 4];
      const float4 whn = *(const float4*)&w_hh[(long)(128 + u) * 64 + k4 * 4];
      ar[j] += x4.x * wir.x + x4.y * wir.y + x4.z * wir.z + x4.w * wir.w
             + h4.x * whr.x + h4.y * whr.y + h4.z * whr.z + h4.w * whr.w;
      az[j] += x4.x * wiz.x + x4.y * wiz.y + x4.z * wiz.z + x4.w * wiz.w
             + h4.x * whz.x + h4.y * whz.y + h4.z * whz.z + h4.w * whz.w;
      ani[j] += x4.x * win.x + x4.y * win.y + x4.z * win.z + x4.w * win.w;
      anh[j] += h4.x * whn.x + h4.y * whn.y + h4.z * whn.z + h4.w * whn.w;
    }
  }

  float q[NACT_];
  #pragma unroll
  for (int c = 0; c < NACT_; ++c) q[c] = 0.0f;

  #pragma unroll
  for (int j = 0; j < 8; ++j) {
    float rg = sigmoidf(ar[j]);
    float zg = sigmoidf(az[j]);
    float ng = tanh_fast(ani[j] + rg * anh[j]);
    float hold = hrow[u0 + j];            // LDS read (original hidden)
    float hnew = (1.0f - zg) * ng + zg * hold;
    h_out[b * HID_ + u0 + j] = hnew;      // 8 consecutive -> 2x dwordx4
    #pragma unroll
    for (int c = 0; c < NACT_; ++c) q[c] += hnew * w_fc2[(u0 + j) * NACT_ + c];
  }
  #pragma unroll
  for (int m = 1; m < 8; m <<= 1) {
    #pragma unroll
    for (int c = 0; c < NACT_; ++c) q[c] += __shfl_xor(q[c], m, 64);
  }
  // lane sub (<5) writes q component sub; cndmask-select (no dynamic reg index)
  float qv = q[0];
  if (sub == 1) qv = q[1];
  if (sub == 2) qv = q[2];
  if (sub == 3) qv = q[3];
  if (sub == 4) qv = q[4];
  if (sub < NACT_) q_out[b * NACT_ + sub] = qv + b_fc2[sub];
}

}  // namespace

extern "C" void kernel_launch(void* const* d_in, const int* in_sizes, int n_in,
                              void* d_out, int out_size, void* d_ws, size_t ws_size,
                              hipStream_t stream) {
  const float* obs    = (const float*)d_in[0];
  const float* hidden = (const float*)d_in[1];
  const float* w_in0  = (const float*)d_in[2];
  const float* b_in0  = (const float*)d_in[3];
  const float* w_in1  = (const float*)d_in[4];
  const float* b_in1  = (const float*)d_in[5];
  const float* w_in2  = (const float*)d_in[6];
  const float* b_in2  = (const float*)d_in[7];
  const float* W      = (const float*)d_in[8];
  const float* a      = (const float*)d_in[9];
  const float* w_o1   = (const float*)d_in[10];
  const float* b_o1   = (const float*)d_in[11];
  const float* w_o2   = (const float*)d_in[12];
  const float* b_o2   = (const float*)d_in[13];
  const float* w_o3   = (const float*)d_in[14];
  const float* b_o3   = (const float*)d_in[15];
  const float* w_fc1  = (const float*)d_in[16];
  const float* b_fc1  = (const float*)d_in[17];
  const float* w_ih   = (const float*)d_in[18];
  const float* w_hh   = (const float*)d_in[19];
  const float* b_ih   = (const float*)d_in[20];
  const float* b_hh   = (const float*)d_in[21];
  const float* w_fc2  = (const float*)d_in[22];
  const float* b_fc2  = (const float*)d_in[23];

  float* q_out = (float*)d_out;                  // (B, 5) flat
  float* h_out = q_out + (long)B_ * NACT_;       // (B, 64) flat
  float* Wa = (float*)d_ws;                      // 128 floats scratch

  precompute_Wa<<<1, 64, 0, stream>>>(W, a, Wa);
  atom_rnn_fused<<<B_ / ROWS_, BLK_, 0, stream>>>(
      obs, hidden, w_in0, b_in0, w_in1, b_in1, w_in2, b_in2, Wa,
      w_o1, b_o1, w_o2, b_o2, w_o3, b_o3, w_fc1, b_fc1,
      w_ih, w_hh, b_ih, b_hh, w_fc2, b_fc2, q_out, h_out);
}